// Round 6
// baseline (1487.823 us; speedup 1.0000x reference)
//
#include <hip/hip_runtime.h>

typedef __attribute__((ext_vector_type(8))) short short8;
typedef __attribute__((ext_vector_type(8))) unsigned short us8;
typedef __attribute__((ext_vector_type(4))) unsigned short us4;
typedef __attribute__((ext_vector_type(4))) float f32x4;

#define FCRIT 3.8415923532

// ---------------- workspace layout (bytes) ----------------
#define OFF_FULL   0u          // double[4][16][2] full-image conv stats
#define OFF_PATCH  1024u       // double[4][64][2] per-layer patch stats
#define OFF_SBUF   8192u       // float[4][4][64][64] logits per layer
#define OFF_BAR    270336u     // barrier counter
#define ZERO_BYTES 270592u
#define OFF_W3H    (1u<<20)              // ushort[3][192][256]
#define OFF_WRH    (OFF_W3H + 294912u)   // ushort[3][256][64]
#define OFF_QCM    (4u<<20)    // ushort[2][4][64][4096]  Q channel-major splits
#define OFF_KBC    (8u<<20)    // ushort[2][4][64][4096]  K channel-major splits
#define OFF_VBT    (12u<<20)   // ushort[2][4][4096][64]  V pixel-major splits
#define OFF_XB     (16u<<20)   // ushort[2][4][4096][256] patch splits [px][c]
#define OFF_PB     (32u<<20)   // float[4][4][4096][256]  P1..P4 pixel-major

#define MFMA __builtin_amdgcn_mfma_f32_16x16x32_bf16

// ---------------- helpers ----------------
static __device__ __forceinline__ unsigned short f2bf(float f) {
  union { float f; unsigned u; } v; v.f = f;
  unsigned r = v.u + 0x7fffu + ((v.u >> 16) & 1u);
  return (unsigned short)(r >> 16);
}
static __device__ __forceinline__ float bf2f(unsigned short h) {
  union { unsigned u; float f; } v; v.u = ((unsigned)h) << 16;
  return v.f;
}
static __device__ __forceinline__ void split2(float v, unsigned short& h, unsigned short& m) {
  h = f2bf(v); float r = v - bf2f(h); m = f2bf(r);
}
static __device__ __forceinline__ double wred(double v) {
#pragma unroll
  for (int off = 32; off > 0; off >>= 1) v += __shfl_down(v, off, 64);
  return v;
}
// device-scope grid barrier; all 512 blocks co-resident (launch_bounds(256,2), 56KB LDS)
static __device__ __forceinline__ void gbar(unsigned* cnt, unsigned target) {
  __syncthreads();
  if (threadIdx.x == 0) {
    __threadfence();
    atomicAdd(cnt, 1u);
    unsigned spins = 0;
    while (__hip_atomic_load(cnt, __ATOMIC_RELAXED, __HIP_MEMORY_SCOPE_AGENT) < target) {
      __builtin_amdgcn_s_sleep(2);
      if (++spins > (1u << 19)) break;   // bailout: fail, don't hang
    }
    __threadfence();
  }
  __syncthreads();
}

// ---------------- the persistent kernel ----------------
__global__ __launch_bounds__(256, 2) void k_giga(
    const float* __restrict__ x,
    const float* __restrict__ Wq, const float* __restrict__ bq,
    const float* __restrict__ Wk, const float* __restrict__ bk,
    const float* __restrict__ Wv, const float* __restrict__ bv,
    const float* __restrict__ Wr, const float* __restrict__ br,
    const float* __restrict__ Wf, const float* __restrict__ bf,
    float* __restrict__ out, char* __restrict__ ws) {
  __shared__ __align__(16) char pool[57344];   // [0,16K)=WfT permanent; rest scratch
  const int t = threadIdx.x;
  const int bid = blockIdx.x;
  double* fullS  = (double*)(ws + OFF_FULL);
  double* patchS = (double*)(ws + OFF_PATCH);
  float* Sb = (float*)(ws + OFF_SBUF);
  unsigned* cnt = (unsigned*)(ws + OFF_BAR);
  unsigned short* W3H = (unsigned short*)(ws + OFF_W3H);
  unsigned short* WRH = (unsigned short*)(ws + OFF_WRH);
  unsigned short* QCM = (unsigned short*)(ws + OFF_QCM);
  unsigned short* KBC = (unsigned short*)(ws + OFF_KBC);
  unsigned short* VBT = (unsigned short*)(ws + OFF_VBT);
  unsigned short* XB  = (unsigned short*)(ws + OFF_XB);
  float* PB = (float*)(ws + OFF_PB);
  const int w = t >> 6, lane = t & 63, lo16 = lane & 15, hi4 = lane >> 4;
  char* scr = pool + 16384;

  // permanent WfT [256c][16o]
  {
    float* WfT2 = (float*)scr;
    for (int r = 0; r < 16; ++r) {
      int idx = r * 256 + t;
      WfT2[(idx >> 8) * 257 + (idx & 255)] = Wf[idx];
    }
    __syncthreads();
    float* WfT = (float*)pool;
    for (int r = 0; r < 16; ++r) {
      int idx = r * 256 + t;
      int c = idx >> 4, o = idx & 15;
      WfT[c * 16 + o] = WfT2[o * 257 + c];
    }
    __syncthreads();
  }

  // ---- copy-ballast: block owns row-pair (cb_b, cb_rp); 13 channel chunks ----
  const int cb_b = bid >> 7, cb_rp = bid & 127;
  const int cb_r0 = cb_rp * 2 + (t >> 7);
  const int cb_col2 = (t & 127) * 2;
  const size_t cb_base = (size_t)cb_b * 16777216 + (size_t)cb_r0 * 256 + cb_col2;
  const bool cb_skipStore = (cb_rp >= 96) && ((t & 127) >= 96);
  float y0[16], y1[16];
#pragma unroll
  for (int o = 0; o < 16; ++o) { y0[o] = 0.f; y1[o] = 0.f; }

  auto copy_chunk = [&](int p) {
    const int c0 = (p * 256) / 13, c1 = ((p + 1) * 256) / 13;
    const float* WfT = (const float*)pool;
    int c = c0;
    for (; c + 4 <= c1; c += 4) {
      double v[4];
#pragma unroll
      for (int u = 0; u < 4; ++u)
        v[u] = *(const double*)(x + cb_base + (size_t)(c + u) * 65536);
#pragma unroll
      for (int u = 0; u < 4; ++u) {
        if (!cb_skipStore)
          __builtin_nontemporal_store(v[u], (double*)(out + cb_base + (size_t)(c + u) * 65536));
        const float2 f = *(const float2*)&v[u];
        const float4* wf = (const float4*)&WfT[(c + u) * 16];
        const float4 w0 = wf[0], w1 = wf[1], w2 = wf[2], w3 = wf[3];
        const float wv[16] = {w0.x, w0.y, w0.z, w0.w, w1.x, w1.y, w1.z, w1.w,
                              w2.x, w2.y, w2.z, w2.w, w3.x, w3.y, w3.z, w3.w};
#pragma unroll
        for (int o = 0; o < 16; ++o) { y0[o] += wv[o] * f.x; y1[o] += wv[o] * f.y; }
      }
    }
    for (; c < c1; ++c) {
      double v = *(const double*)(x + cb_base + (size_t)c * 65536);
      if (!cb_skipStore)
        __builtin_nontemporal_store(v, (double*)(out + cb_base + (size_t)c * 65536));
      const float2 f = *(const float2*)&v;
      const float4* wf = (const float4*)&WfT[c * 16];
      const float4 w0 = wf[0], w1 = wf[1], w2 = wf[2], w3 = wf[3];
      const float wv[16] = {w0.x, w0.y, w0.z, w0.w, w1.x, w1.y, w1.z, w1.w,
                            w2.x, w2.y, w2.z, w2.w, w3.x, w3.y, w3.z, w3.w};
#pragma unroll
      for (int o = 0; o < 16; ++o) { y0[o] += wv[o] * f.x; y1[o] += wv[o] * f.y; }
    }
  };

  const int rb = bid >> 6;   // attn-role b (bid<256)
  const int ry = bid & 63;   // attn-role y / nt / a

  auto patch_reduce = [&](int slot) {
    const int oo = t & 15, pxg = t >> 4;
    const float* part = (const float*)scr;
    double s1 = 0.0, s2 = 0.0;
    const float bo = bf[oo];
#pragma unroll
    for (int j = 0; j < 4; ++j) {
      const int p = pxg * 4 + j;
      const float yv = part[p * 17 + oo] + part[(64 + p) * 17 + oo]
                     + part[(128 + p) * 17 + oo] + part[(192 + p) * 17 + oo] + bo;
      const double vd = (double)yv;
      s1 += vd; s2 += vd * vd;
    }
    double* red = (double*)(scr + 17408);
    red[(oo * 16 + pxg) * 2] = s1;
    red[(oo * 16 + pxg) * 2 + 1] = s2;
    __syncthreads();
    if (t < 32) {
      const int o = t >> 1, wh = t & 1;
      double s = 0.0;
#pragma unroll
      for (int g = 0; g < 16; ++g) s += red[(o * 16 + g) * 2 + wh];
      unsafeAtomicAdd(&patchS[(size_t)slot * 128 + (rb * 16 + o) * 2 + wh], s);
    }
  };

  // =============== PHASE 0: copy c0 + (xcvt0+stats0 | wcvt) ===============
  copy_chunk(0);
  if (bid < 256) {
    const int px = t & 63, cg = t >> 6;
    const float* WfT = (const float*)pool;
    float* part = (float*)scr;
    float po[16];
#pragma unroll
    for (int o = 0; o < 16; ++o) po[o] = 0.f;
    const size_t xb0 = ((size_t)rb * 256 + cg * 64) * 65536 + (size_t)(192 + ry) * 256 + 192 + px;
    unsigned short* xh = XB + ((size_t)rb * 4096 + ry * 64 + px) * 256 + cg * 64;
    for (int g = 0; g < 8; ++g) {
      us8 hv, mv;
#pragma unroll
      for (int j = 0; j < 8; ++j) {
        const int c = g * 8 + j;
        const float v = x[xb0 + (size_t)c * 65536];
        unsigned short h, m; split2(v, h, m);
        hv[j] = h; mv[j] = m;
        const float* wc = &WfT[(cg * 64 + c) * 16];
#pragma unroll
        for (int o = 0; o < 16; ++o) po[o] += wc[o] * v;
      }
      *(us8*)(xh + g * 8) = hv;
      *(us8*)(xh + 4194304 + g * 8) = mv;
    }
#pragma unroll
    for (int o = 0; o < 16; ++o) part[(cg * 64 + px) * 17 + o] = po[o];
    __syncthreads();
    patch_reduce(0);
  } else {
    const int idx = (bid - 256) * 256 + t;   // 0..65535
    float v; unsigned short* dst; int stride;
    if (idx < 49152) {
      const int row = idx >> 8, col = idx & 255;
      v = (row < 64) ? Wq[row * 256 + col]
        : (row < 128) ? Wk[(row - 64) * 256 + col]
                      : Wv[(row - 128) * 256 + col];
      dst = W3H + idx; stride = 49152;
    } else {
      const int j = idx - 49152;
      v = Wr[j]; dst = WRH + j; stride = 16384;
    }
    const unsigned short h = f2bf(v); const float r1 = v - bf2f(h);
    const unsigned short m = f2bf(r1); const float r2 = r1 - bf2f(m);
    dst[0] = h; dst[stride] = m; dst[2 * stride] = f2bf(r2);
  }
  unsigned seq = 1;
  gbar(cnt, 512 * seq);

  // =============== LAYERS: 3 phases each ===============
  for (int l = 0; l < 4; ++l) {
    // ---- Pq: QKV = W3 @ P_l  (block = pixel-row nt) ----
    copy_chunk(1 + 3 * l);
    if (bid < 256) {
      const int b = rb, nt = ry;
      unsigned short* Wst = (unsigned short*)scr;            // [2][192][40]
      unsigned short* Xst = (unsigned short*)(scr + 30720);  // [2][64][40]
      f32x4 acc[12];
#pragma unroll
      for (int mf = 0; mf < 12; ++mf) acc[mf] = (f32x4)0.f;
      const unsigned short* Xbase = XB + ((size_t)b * 4096 + nt * 64) * 256;
      for (int kc = 0; kc < 8; ++kc) {
        const int k0 = kc * 32;
        __syncthreads();
#pragma unroll
        for (int lev = 0; lev < 2; ++lev) {
#pragma unroll
          for (int r = 0; r < 3; ++r) {
            const int u = r * 256 + t;
            const int m = u >> 2, k8 = (u & 3) * 8;
            *(us8*)&Wst[lev * 7680 + m * 40 + k8] =
                *(const us8*)(W3H + lev * 49152 + m * 256 + k0 + k8);
          }
          { const int m = t >> 2, k8 = (t & 3) * 8;
            *(us8*)&Xst[lev * 2560 + m * 40 + k8] =
                *(const us8*)(Xbase + (size_t)lev * 4194304 + (size_t)m * 256 + k0 + k8); }
        }
        __syncthreads();
        const short8 xh8 = *(const short8*)&Xst[(w * 16 + lo16) * 40 + hi4 * 8];
        const short8 xm8 = *(const short8*)&Xst[2560 + (w * 16 + lo16) * 40 + hi4 * 8];
#pragma unroll
        for (int mf = 0; mf < 12; ++mf) {
          const int m = mf * 16 + lo16;
          const short8 wh8 = *(const short8*)&Wst[m * 40 + hi4 * 8];
          const short8 wm8 = *(const short8*)&Wst[7680 + m * 40 + hi4 * 8];
          const short8 wl8 = *(const short8*)(W3H + 2 * 49152 + m * 256 + k0 + hi4 * 8);
          f32x4 c = acc[mf];
          c = MFMA(wh8, xh8, c, 0, 0, 0);
          c = MFMA(wh8, xm8, c, 0, 0, 0);
          c = MFMA(wm8, xh8, c, 0, 0, 0);
          c = MFMA(wm8, xm8, c, 0, 0, 0);
          c = MFMA(wl8, xh8, c, 0, 0, 0);
          acc[mf] = c;
        }
      }
      __syncthreads();
      // epilogue: Q,K -> LDS [ch][px]; V -> VBT pixel-major
      unsigned short* QL = (unsigned short*)scr;             // [2][64][80]
      unsigned short* KL = (unsigned short*)(scr + 20480);   // [2][64][80]
      const int px = w * 16 + lo16;
#pragma unroll
      for (int mf = 0; mf < 12; ++mf) {
        const int m0 = mf * 16 + hi4 * 4;
        if (mf < 4) {
#pragma unroll
          for (int r = 0; r < 4; ++r) {
            unsigned short h, m2; split2(acc[mf][r] + bq[m0 + r], h, m2);
            QL[(m0 + r) * 80 + px] = h; QL[5120 + (m0 + r) * 80 + px] = m2;
          }
        } else if (mf < 8) {
#pragma unroll
          for (int r = 0; r < 4; ++r) {
            unsigned short h, m2; split2(acc[mf][r] + bk[m0 - 64 + r], h, m2);
            KL[(m0 - 64 + r) * 80 + px] = h; KL[5120 + (m0 - 64 + r) * 80 + px] = m2;
          }
        } else {
          us4 hv, mv;
#pragma unroll
          for (int r = 0; r < 4; ++r) {
            unsigned short h, m2; split2(acc[mf][r] + bv[m0 - 128 + r], h, m2);
            hv[r] = h; mv[r] = m2;
          }
          const size_t vo = ((size_t)b * 4096 + nt * 64 + px) * 64 + (m0 - 128);
          *(us4*)(VBT + vo) = hv;
          *(us4*)(VBT + 1048576 + vo) = mv;
        }
      }
      __syncthreads();
      // coalesced transpose-write: Q_cm, KBC channel-major
      { const int ch = t >> 2, px0 = (t & 3) * 16;
#pragma unroll
        for (int lev = 0; lev < 2; ++lev) {
          const us8 q0 = *(const us8*)&QL[lev * 5120 + ch * 80 + px0];
          const us8 q1 = *(const us8*)&QL[lev * 5120 + ch * 80 + px0 + 8];
          unsigned short* qd = QCM + (size_t)lev * 1048576 + ((size_t)b * 64 + ch) * 4096 + nt * 64 + px0;
          *(us8*)qd = q0; *(us8*)(qd + 8) = q1;
          const us8 k0v = *(const us8*)&KL[lev * 5120 + ch * 80 + px0];
          const us8 k1v = *(const us8*)&KL[lev * 5120 + ch * 80 + px0 + 8];
          unsigned short* kd = KBC + (size_t)lev * 1048576 + ((size_t)b * 64 + ch) * 4096 + nt * 64 + px0;
          *(us8*)kd = k0v; *(us8*)(kd + 8) = k1v;
        } }
    }
    ++seq; gbar(cnt, 512 * seq);

    // ---- Ps: S[i][j] += sum_c Q[i][64a+c] * Kconv[a][64c+j]  (block = channel a) ----
    copy_chunk(2 + 3 * l);
    if (bid < 256) {
      const int b = rb, a = ry;
      unsigned short* KL2 = (unsigned short*)scr;  // [2][4096]
      { const int off = t * 16;
#pragma unroll
        for (int lev = 0; lev < 2; ++lev) {
          const us8 v0 = *(const us8*)(KBC + (size_t)lev * 1048576 + ((size_t)b * 64 + a) * 4096 + off);
          const us8 v1 = *(const us8*)(KBC + (size_t)lev * 1048576 + ((size_t)b * 64 + a) * 4096 + off + 8);
          *(us8*)&KL2[lev * 4096 + off] = v0;
          *(us8*)&KL2[lev * 4096 + off + 8] = v1;
        } }
      __syncthreads();
      f32x4 sacc[4];
#pragma unroll
      for (int jf = 0; jf < 4; ++jf) sacc[jf] = (f32x4)0.f;
#pragma unroll
      for (int kc = 0; kc < 2; ++kc) {
        const size_t qoff = ((size_t)b * 64 + w * 16 + lo16) * 4096 + a * 64 + kc * 32 + hi4 * 8;
        const short8 qh = *(const short8*)(QCM + qoff);
        const short8 qm = *(const short8*)(QCM + 1048576 + qoff);
#pragma unroll
        for (int jf = 0; jf < 4; ++jf) {
          short8 kh, km;
#pragma unroll
          for (int u = 0; u < 8; ++u) {
            const int idx = (kc * 32 + hi4 * 8 + u) * 64 + jf * 16 + lo16;
            kh[u] = (short)KL2[idx];
            km[u] = (short)KL2[4096 + idx];
          }
          f32x4 c = sacc[jf];
          c = MFMA(qh, kh, c, 0, 0, 0);
          c = MFMA(qh, km, c, 0, 0, 0);
          c = MFMA(qm, kh, c, 0, 0, 0);
          c = MFMA(qm, km, c, 0, 0, 0);
          sacc[jf] = c;
        }
      }
      float* Sl = Sb + ((size_t)l * 4 + b) * 4096;
#pragma unroll
      for (int jf = 0; jf < 4; ++jf)
#pragma unroll
        for (int r = 0; r < 4; ++r)
          unsafeAtomicAdd(&Sl[(w * 16 + hi4 * 4 + r) * 64 + jf * 16 + lo16], sacc[jf][r]);
    }
    ++seq; gbar(cnt, 512 * seq);

    // ---- Pa: softmax + A=wts@V + P'=Wr@A+br+P + (xcvt+stats l+1) ----
    copy_chunk(3 + 3 * l);
    if (bid < 256) {
      const int b = rb, y = ry;
      float* Sf = (float*)scr;                                // [64][68]
      unsigned short* wtsL = (unsigned short*)(scr + 20480);  // [2][64][80]
      const float* Sl = Sb + ((size_t)l * 4 + b) * 4096;
      { const int i2 = t >> 2, jg = (t & 3) * 16;
#pragma unroll
        for (int u = 0; u < 4; ++u) {
          const float4 v = *(const float4*)(Sl + i2 * 64 + jg + u * 4);
          Sf[(jg + u * 4 + 0) * 68 + i2] = v.x;
          Sf[(jg + u * 4 + 1) * 68 + i2] = v.y;
          Sf[(jg + u * 4 + 2) * 68 + i2] = v.z;
          Sf[(jg + u * 4 + 3) * 68 + i2] = v.w;
        } }
      __syncthreads();
      if (t < 64) {
        float* rowp = &Sf[t * 68];
        float mx = -1e30f;
#pragma unroll
        for (int i = 0; i < 64; ++i) mx = fmaxf(mx, rowp[i]);
        float sum = 0.f;
#pragma unroll
        for (int i = 0; i < 64; ++i) {
          const float e = __expf(rowp[i] - mx);
          rowp[i] = e; sum += e;
        }
        const float inv = 1.f / sum;
#pragma unroll
        for (int i = 0; i < 64; ++i) rowp[i] *= inv;
      }
      __syncthreads();
      { const int i2 = t >> 2, jg = (t & 3) * 16;
#pragma unroll
        for (int u = 0; u < 2; ++u) {
          us8 hv, mv;
#pragma unroll
          for (int jj = 0; jj < 8; ++jj) {
            unsigned short h, m; split2(Sf[(jg + u * 8 + jj) * 68 + i2], h, m);
            hv[jj] = h; mv[jj] = m;
          }
          *(us8*)&wtsL[i2 * 80 + jg + u * 8] = hv;
          *(us8*)&wtsL[5120 + i2 * 80 + jg + u * 8] = mv;
        } }
      __syncthreads();
      const int pxw = w * 16 + lo16;
      f32x4 aacc[4];
#pragma unroll
      for (int if4 = 0; if4 < 4; ++if4) aacc[if4] = (f32x4)0.f;
      const size_t vrow = ((size_t)b * 4096 + y * 64 + pxw) * 64;
#pragma unroll
      for (int kc = 0; kc < 2; ++kc) {
        const short8 vh = *(const short8*)(VBT + vrow + kc * 32 + hi4 * 8);
        const short8 vm = *(const short8*)(VBT + 1048576 + vrow + kc * 32 + hi4 * 8);
#pragma unroll
        for (int if4 = 0; if4 < 4; ++if4) {
          const short8 wh = *(const short8*)&wtsL[(if4 * 16 + lo16) * 80 + kc * 32 + hi4 * 8];
          const short8 wm = *(const short8*)&wtsL[5120 + (if4 * 16 + lo16) * 80 + kc * 32 + hi4 * 8];
          f32x4 c = aacc[if4];
          c = MFMA(wh, vh, c, 0, 0, 0);
          c = MFMA(wh, vm, c, 0, 0, 0);
          c = MFMA(wm, vh, c, 0, 0, 0);
          c = MFMA(wm, vm, c, 0, 0, 0);
          aacc[if4] = c;
        }
      }
      __syncthreads();
      unsigned short* AL = (unsigned short*)scr;   // [2][64px][80i]
#pragma unroll
      for (int if4 = 0; if4 < 4; ++if4)
#pragma unroll
        for (int r = 0; r < 4; ++r) {
          unsigned short h, m; split2(aacc[if4][r], h, m);
          AL[pxw * 80 + if4 * 16 + hi4 * 4 + r] = h;
          AL[5120 + pxw * 80 + if4 * 16 + hi4 * 4 + r] = m;
        }
      __syncthreads();
      f32x4 oacc[16];
#pragma unroll
      for (int of = 0; of < 16; ++of) oacc[of] = (f32x4)0.f;
#pragma unroll
      for (int kc = 0; kc < 2; ++kc) {
        const short8 ah = *(const short8*)&AL[pxw * 80 + kc * 32 + hi4 * 8];
        const short8 am = *(const short8*)&AL[5120 + pxw * 80 + kc * 32 + hi4 * 8];
#pragma unroll
        for (int of = 0; of < 16; ++of) {
          const int o = of * 16 + lo16;
          const short8 rh = *(const short8*)(WRH + o * 64 + kc * 32 + hi4 * 8);
          const short8 rm = *(const short8*)(WRH + 16384 + o * 64 + kc * 32 + hi4 * 8);
          const short8 rl = *(const short8*)(WRH + 32768 + o * 64 + kc * 32 + hi4 * 8);
          f32x4 c = oacc[of];
          c = MFMA(rh, ah, c, 0, 0, 0);
          c = MFMA(rh, am, c, 0, 0, 0);
          c = MFMA(rm, ah, c, 0, 0, 0);
          c = MFMA(rm, am, c, 0, 0, 0);
          c = MFMA(rl, ah, c, 0, 0, 0);
          oacc[of] = c;
        }
      }
      float* PL = (float*)(scr + 20480);
      float* PBl = PB + (size_t)l * 4194304;
      const float* WfT = (const float*)pool;
      const float* prevP = PB + (size_t)(l - 1) * 4194304;
      float po[16];
#pragma unroll
      for (int o = 0; o < 16; ++o) po[o] = 0.f;
      const int px = t & 63, cgq = t >> 6;
      const int c16 = cgq * 16;
      for (int oc = 0; oc < 4; ++oc) {
        __syncthreads();
#pragma unroll
        for (int q = 0; q < 4; ++q) {
          const int of = oc * 4 + q;
#pragma unroll
          for (int r = 0; r < 4; ++r)
            PL[pxw * 68 + q * 16 + hi4 * 4 + r] = oacc[of][r] + br[oc * 64 + q * 16 + hi4 * 4 + r];
        }
        __syncthreads();
        float vals[16];
        if (l == 0) {
          const size_t xb0 = ((size_t)b * 256 + oc * 64 + c16) * 65536
                           + (size_t)(192 + y) * 256 + 192 + px;
#pragma unroll
          for (int cc = 0; cc < 16; ++cc)
            vals[cc] = PL[px * 68 + c16 + cc] + x[xb0 + (size_t)cc * 65536];
        } else {
          const float* pp = prevP + ((size_t)b * 4096 + y * 64 + px) * 256 + oc * 64 + c16;
#pragma unroll
          for (int u = 0; u < 4; ++u) {
            const float4 pv = *(const float4*)(pp + u * 4);
            vals[u * 4 + 0] = PL[px * 68 + c16 + u * 4 + 0] + pv.x;
            vals[u * 4 + 1] = PL[px * 68 + c16 + u * 4 + 1] + pv.y;
            vals[u * 4 + 2] = PL[px * 68 + c16 + u * 4 + 2] + pv.z;
            vals[u * 4 + 3] = PL[px * 68 + c16 + u * 4 + 3] + pv.w;
          }
        }
        float* dstP = PBl + ((size_t)b * 4096 + y * 64 + px) * 256 + oc * 64 + c16;
#pragma unroll
        for (int u = 0; u < 4; ++u) {
          float4 fv;
          fv.x = vals[u * 4 + 0]; fv.y = vals[u * 4 + 1];
          fv.z = vals[u * 4 + 2]; fv.w = vals[u * 4 + 3];
          *(float4*)(dstP + u * 4) = fv;
        }
        if (l < 3) {
          unsigned short* xdst = XB + ((size_t)b * 4096 + y * 64 + px) * 256 + oc * 64 + c16;
          us8 hv[2], mv[2];
#pragma unroll
          for (int cc = 0; cc < 16; ++cc) {
            unsigned short h, m; split2(vals[cc], h, m);
            hv[cc >> 3][cc & 7] = h; mv[cc >> 3][cc & 7] = m;
            const float* wc = &WfT[(oc * 64 + c16 + cc) * 16];
#pragma unroll
            for (int o = 0; o < 16; ++o) po[o] += wc[o] * vals[cc];
          }
          *(us8*)xdst = hv[0]; *(us8*)(xdst + 8) = hv[1];
          *(us8*)(xdst + 4194304) = mv[0]; *(us8*)(xdst + 4194304 + 8) = mv[1];
        }
      }
      if (l < 3) {
        __syncthreads();
        float* part = (float*)scr;
#pragma unroll
        for (int o = 0; o < 16; ++o) part[(cgq * 64 + px) * 17 + o] = po[o];
        __syncthreads();
        patch_reduce(l + 1);
      }
    }
    ++seq; gbar(cnt, 512 * seq);
  }

  // =============== finalize full-image stats ===============
  {
    double* sm = (double*)scr;
#pragma unroll 1
    for (int o = 0; o < 16; ++o) {
      const float bo = bf[o];
      const double a0 = (double)(y0[o] + bo), a1 = (double)(y1[o] + bo);
      double s1 = a0 + a1, s2 = a0 * a0 + a1 * a1;
      const double r1 = wred(s1), r2 = wred(s2);
      if (lane == 0) { sm[(w * 16 + o) * 2] = r1; sm[(w * 16 + o) * 2 + 1] = r2; }
    }
    __syncthreads();
    if (t < 32) {
      const int o = t >> 1, wh = t & 1;
      double s = sm[o * 2 + wh] + sm[(16 + o) * 2 + wh]
               + sm[(32 + o) * 2 + wh] + sm[(48 + o) * 2 + wh];
      unsafeAtomicAdd(&fullS[(cb_b * 16 + o) * 2 + wh], s);
    }
  }
  ++seq; gbar(cnt, 512 * seq);

  // =============== decision + select ===============
  int jsel = 4;
  {
    const int k = lane;
    const double fs = fullS[2 * k], fq = fullS[2 * k + 1];
    const double m2 = fs * (1.0 / 65536.0);
    const double v2 = fq * (1.0 / 65536.0) - m2 * m2;
#pragma unroll
    for (int l = 0; l < 4; ++l) {
      const double* ps = patchS + (size_t)l * 128;
      const double s1 = ps[2 * k], s2 = ps[2 * k + 1];
      const double m1 = s1 * (1.0 / 4096.0);
      const double v1 = s2 * (1.0 / 4096.0) - m1 * m1;
      const double gm = (4096.0 * m1 + 65536.0 * m2) * (1.0 / 69632.0);
      const double d1 = m1 - gm, d2 = m2 - gm;
      const double ssb = 4096.0 * d1 * d1 + 65536.0 * d2 * d2;
      const double ssw = 4096.0 * v1 + 65536.0 * v2;
      const double F = ssb * (69630.0 / ssw);
      const unsigned long long bal = __ballot(F > FCRIT);
      if (2 * __popcll(bal) >= 64 && jsel == 4) jsel = l;
    }
  }
  if (bid < 256) {
    const int b2 = rb, y = ry;
    if (jsel == 0) {
      const int px = t & 63, cg = t >> 6;
      for (int c = cg * 64; c < cg * 64 + 64; ++c) {
        const size_t o = (((size_t)b2 * 256 + c) * 256 + 192 + y) * 256 + 192 + px;
        out[o] = x[o];
      }
    } else {
      const float* src = PB + (size_t)(jsel - 1) * 4194304;
      float* T = (float*)scr;   // [64][68]
      for (int oc = 0; oc < 4; ++oc) {
        __syncthreads();
        { const int pxl = t >> 2, og = (t & 3) * 16;
#pragma unroll
          for (int u = 0; u < 4; ++u) {
            const float4 v = *(const float4*)(src + ((size_t)b2 * 4096 + y * 64 + pxl) * 256
                                              + oc * 64 + og + u * 4);
            *(float4*)&T[pxl * 68 + og + u * 4] = v;
          } }
        __syncthreads();
        { const int ol = t & 63, pg = t >> 6;
          float* op = out + (((size_t)b2 * 256 + oc * 64 + ol) * 256 + 192 + y) * 256 + 192 + pg * 16;
#pragma unroll
          for (int u4 = 0; u4 < 4; ++u4) {
            float4 v;
            v.x = T[(pg * 16 + u4 * 4 + 0) * 68 + ol];
            v.y = T[(pg * 16 + u4 * 4 + 1) * 68 + ol];
            v.z = T[(pg * 16 + u4 * 4 + 2) * 68 + ol];
            v.w = T[(pg * 16 + u4 * 4 + 3) * 68 + ol];
            *(float4*)(op + u4 * 4) = v;
          } }
      }
    }
  }
}

// ---------------- launch ----------------
extern "C" void kernel_launch(void* const* d_in, const int* in_sizes, int n_in,
                              void* d_out, int out_size, void* d_ws, size_t ws_size,
                              hipStream_t stream) {
  const float* x  = (const float*)d_in[0];
  const float* Wq = (const float*)d_in[1];
  const float* bq = (const float*)d_in[2];
  const float* Wk = (const float*)d_in[3];
  const float* bk = (const float*)d_in[4];
  const float* Wv = (const float*)d_in[5];
  const float* bv = (const float*)d_in[6];
  const float* Wr = (const float*)d_in[7];
  const float* br = (const float*)d_in[8];
  const float* Wf = (const float*)d_in[9];
  const float* bf = (const float*)d_in[10];
  float* out = (float*)d_out;
  char* ws = (char*)d_ws;

  (void)hipMemsetAsync(ws, 0, ZERO_BYTES, stream);
  k_giga<<<512, 256, 0, stream>>>(x, Wq, bq, Wk, bk, Wv, bv, Wr, br, Wf, bf, out, ws);
}

// Round 7
// 423.301 us; speedup vs baseline: 3.5148x; 3.5148x over previous
//
#include <hip/hip_runtime.h>

typedef __attribute__((ext_vector_type(8))) short short8;
typedef __attribute__((ext_vector_type(8))) unsigned short us8;
typedef __attribute__((ext_vector_type(4))) unsigned short us4;
typedef __attribute__((ext_vector_type(4))) float f32x4;

#define FCRIT 3.8415923532

// ---------------- workspace layout (bytes) ----------------
#define OFF_FULL   0u          // double[4][16][2] full-image conv stats
#define OFF_PATCH  1024u       // double[4][64][2] per-layer patch stats (slot l = stats of P_l)
#define OFF_SBUF   8192u       // float[4][4][64][64] logits per layer
#define ZERO_BYTES 270336u
#define OFF_W3H    (1u<<20)              // ushort[3][192][256]
#define OFF_WRH    (OFF_W3H + 294912u)   // ushort[3][256][64]
#define OFF_QCM    (4u<<20)    // ushort[2][4][64][4096]  Q channel-major splits
#define OFF_KBC    (8u<<20)    // ushort[2][4][64][4096]  K channel-major splits
#define OFF_VBT    (12u<<20)   // ushort[2][4][4096][64]  V pixel-major splits
#define OFF_PB     (32u<<20)   // float[4][4][4096][256]  P1..P4 pixel-major

#define MFMA __builtin_amdgcn_mfma_f32_16x16x32_bf16

// ---------------- helpers ----------------
static __device__ __forceinline__ unsigned short f2bf(float f) {
  union { float f; unsigned u; } v; v.f = f;
  unsigned r = v.u + 0x7fffu + ((v.u >> 16) & 1u);
  return (unsigned short)(r >> 16);
}
static __device__ __forceinline__ float bf2f(unsigned short h) {
  union { unsigned u; float f; } v; v.u = ((unsigned)h) << 16;
  return v.f;
}
static __device__ __forceinline__ void split2(float v, unsigned short& h, unsigned short& m) {
  h = f2bf(v); float r = v - bf2f(h); m = f2bf(r);
}
static __device__ __forceinline__ double wred(double v) {
#pragma unroll
  for (int off = 32; off > 0; off >>= 1) v += __shfl_down(v, off, 64);
  return v;
}

// ---------------- weight conversion: 3-level splits of W3 | Wr ----------------
__global__ __launch_bounds__(256) void k_wcvt(const float* __restrict__ Wq,
                                              const float* __restrict__ Wk,
                                              const float* __restrict__ Wv,
                                              const float* __restrict__ Wr,
                                              char* __restrict__ ws) {
  unsigned short* W3H = (unsigned short*)(ws + OFF_W3H);
  unsigned short* WRH = (unsigned short*)(ws + OFF_WRH);
  const int idx = blockIdx.x * 256 + threadIdx.x;   // 0..65535
  float v; unsigned short* dst; int stride;
  if (idx < 49152) {
    const int row = idx >> 8, col = idx & 255;
    v = (row < 64) ? Wq[row * 256 + col]
      : (row < 128) ? Wk[(row - 64) * 256 + col]
                    : Wv[(row - 128) * 256 + col];
    dst = W3H + idx; stride = 49152;
  } else {
    const int j = idx - 49152;
    v = Wr[j]; dst = WRH + j; stride = 16384;
  }
  const unsigned short h = f2bf(v); const float r1 = v - bf2f(h);
  const unsigned short m = f2bf(r1); const float r2 = r1 - bf2f(m);
  dst[0] = h; dst[stride] = m; dst[2 * stride] = f2bf(r2);
}

// ---------------- fused copy + full-image conv stats + slot-0 patch stats ----------------
// (round-3-verified) grid = 512 (b, row-pair), 256 threads.
__global__ __launch_bounds__(256) void k_main(const float* __restrict__ x,
                                              const float* __restrict__ Wf,
                                              const float* __restrict__ bf,
                                              float* __restrict__ out,
                                              double* __restrict__ fullS,
                                              double* __restrict__ patchS0) {
  __shared__ __align__(16) float WfT2[16 * 257];
  __shared__ __align__(16) float WfT[256 * 16];
  __shared__ double sm[4][16][2];
  __shared__ double sp[4][16][2];
  const int t = threadIdx.x;
  const int bb = blockIdx.x >> 7;
  const int rp = blockIdx.x & 127;

  for (int r = 0; r < 16; ++r) {
    int idx = r * 256 + t;
    WfT2[(idx >> 8) * 257 + (idx & 255)] = Wf[idx];
  }
  __syncthreads();
  for (int r = 0; r < 16; ++r) {
    int idx = r * 256 + t;
    int c = idx >> 4, o = idx & 15;
    WfT[c * 16 + o] = WfT2[o * 257 + c];
  }
  __syncthreads();

  const int r0 = rp * 2 + (t >> 7);
  const int col2 = (t & 127) * 2;
  const size_t base = (size_t)bb * 16777216 + (size_t)r0 * 256 + col2;
  const float* xp = x + base;
  float* op = out + base;
  const bool pStore = (rp >= 96) && ((t & 127) >= 96);

  float y0[16], y1[16];
#pragma unroll
  for (int o = 0; o < 16; ++o) { y0[o] = 0.f; y1[o] = 0.f; }

  for (int cb = 0; cb < 32; ++cb) {
    double v[8];
#pragma unroll
    for (int u = 0; u < 8; ++u)
      v[u] = *reinterpret_cast<const double*>(xp + (size_t)(cb * 8 + u) * 65536);
#pragma unroll
    for (int u = 0; u < 8; ++u) {
      double* dst = reinterpret_cast<double*>(op + (size_t)(cb * 8 + u) * 65536);
      if (pStore) *dst = v[u];
      else __builtin_nontemporal_store(v[u], dst);
      const int c = cb * 8 + u;
      float2 f = *reinterpret_cast<const float2*>(&v[u]);
      const float4* wf = reinterpret_cast<const float4*>(&WfT[c * 16]);
      const float4 w0 = wf[0], w1 = wf[1], w2 = wf[2], w3 = wf[3];
      const float wv[16] = {w0.x, w0.y, w0.z, w0.w, w1.x, w1.y, w1.z, w1.w,
                            w2.x, w2.y, w2.z, w2.w, w3.x, w3.y, w3.z, w3.w};
#pragma unroll
      for (int o = 0; o < 16; ++o) {
        y0[o] += wv[o] * f.x;
        y1[o] += wv[o] * f.y;
      }
    }
  }

  const int w = t >> 6, lane = t & 63;
  const bool pBlock = (rp >= 96);
  const bool pLane = ((t & 127) >= 96);
#pragma unroll 1
  for (int o = 0; o < 16; ++o) {
    const float bo = bf[o];
    const double a0 = (double)(y0[o] + bo), a1 = (double)(y1[o] + bo);
    double s1 = a0 + a1, s2 = a0 * a0 + a1 * a1;
    const double r1 = wred(s1), r2 = wred(s2);
    if (lane == 0) { sm[w][o][0] = r1; sm[w][o][1] = r2; }
    if (pBlock) {
      double p1 = pLane ? s1 : 0.0, p2 = pLane ? s2 : 0.0;
      p1 = wred(p1); p2 = wred(p2);
      if (lane == 0) { sp[w][o][0] = p1; sp[w][o][1] = p2; }
    }
  }
  __syncthreads();
  if (t < 32) {
    const int o = t >> 1, wh = t & 1;
    double s = sm[0][o][wh] + sm[1][o][wh] + sm[2][o][wh] + sm[3][o][wh];
    unsafeAtomicAdd(&fullS[(bb * 16 + o) * 2 + wh], s);
    if (pBlock) {
      double p = sp[0][o][wh] + sp[1][o][wh] + sp[2][o][wh] + sp[3][o][wh];
      unsafeAtomicAdd(&patchS0[(bb * 16 + o) * 2 + wh], p);
    }
  }
}

// ---------------- kA: QKV = W3 @ P_l (block = (b, pixel-row nt)), fp32 source, in-LDS split ----------------
__global__ __launch_bounds__(256) void k_qkvA(const float* __restrict__ x,
                                              const float* __restrict__ bq,
                                              const float* __restrict__ bk,
                                              const float* __restrict__ bv,
                                              char* __restrict__ ws, int layer) {
  __shared__ __align__(16) char pool[40960];
  unsigned short* W3H = (unsigned short*)(ws + OFF_W3H);
  unsigned short* QCM = (unsigned short*)(ws + OFF_QCM);
  unsigned short* KBC = (unsigned short*)(ws + OFF_KBC);
  unsigned short* VBT = (unsigned short*)(ws + OFF_VBT);
  const float* PB = (const float*)(ws + OFF_PB);
  const int t = threadIdx.x;
  const int b = blockIdx.x >> 6, nt = blockIdx.x & 63;
  const int w = t >> 6, lane = t & 63, lo16 = lane & 15, hi4 = lane >> 4;

  unsigned short* Wst = (unsigned short*)pool;            // [2][192][40]
  unsigned short* Xst = (unsigned short*)(pool + 30720);  // [2][64][40]
  f32x4 acc[12];
#pragma unroll
  for (int mf = 0; mf < 12; ++mf) acc[mf] = (f32x4)0.f;

  const float* Psrc = PB + (size_t)(layer - 1) * 4194304;  // valid layer>0
  for (int kc = 0; kc < 8; ++kc) {
    const int k0 = kc * 32;
    __syncthreads();
    // stage W3 splits (levels 0,1)
#pragma unroll
    for (int lev = 0; lev < 2; ++lev)
#pragma unroll
      for (int r = 0; r < 3; ++r) {
        const int u = r * 256 + t;
        const int m = u >> 2, k8 = (u & 3) * 8;
        *(us8*)&Wst[lev * 7680 + m * 40 + k8] =
            *(const us8*)(W3H + lev * 49152 + m * 256 + k0 + k8);
      }
    // stage X (fp32 -> 2-level bf16 split in LDS)
    if (layer == 0) {
      const int px = t & 63, csub = t >> 6;
      const size_t xb = ((size_t)b * 256 + k0 + csub * 8) * 65536
                      + (size_t)(192 + nt) * 256 + 192 + px;
#pragma unroll
      for (int j = 0; j < 8; ++j) {
        unsigned short h, m; split2(x[xb + (size_t)j * 65536], h, m);
        Xst[px * 40 + csub * 8 + j] = h;
        Xst[2560 + px * 40 + csub * 8 + j] = m;
      }
    } else {
      const int px = t >> 2, cs = (t & 3) * 8;
      const float* pp = Psrc + ((size_t)b * 4096 + nt * 64 + px) * 256 + k0 + cs;
      const float4 v0 = *(const float4*)pp;
      const float4 v1 = *(const float4*)(pp + 4);
      const float vv[8] = {v0.x, v0.y, v0.z, v0.w, v1.x, v1.y, v1.z, v1.w};
#pragma unroll
      for (int j = 0; j < 8; ++j) {
        unsigned short h, m; split2(vv[j], h, m);
        Xst[px * 40 + cs + j] = h;
        Xst[2560 + px * 40 + cs + j] = m;
      }
    }
    __syncthreads();
    const short8 xh8 = *(const short8*)&Xst[(w * 16 + lo16) * 40 + hi4 * 8];
    const short8 xm8 = *(const short8*)&Xst[2560 + (w * 16 + lo16) * 40 + hi4 * 8];
#pragma unroll
    for (int mf = 0; mf < 12; ++mf) {
      const int m = mf * 16 + lo16;
      const short8 wh8 = *(const short8*)&Wst[m * 40 + hi4 * 8];
      const short8 wm8 = *(const short8*)&Wst[7680 + m * 40 + hi4 * 8];
      const short8 wl8 = *(const short8*)(W3H + 2 * 49152 + m * 256 + k0 + hi4 * 8);
      f32x4 c = acc[mf];
      c = MFMA(wh8, xh8, c, 0, 0, 0);
      c = MFMA(wh8, xm8, c, 0, 0, 0);
      c = MFMA(wm8, xh8, c, 0, 0, 0);
      c = MFMA(wm8, xm8, c, 0, 0, 0);
      c = MFMA(wl8, xh8, c, 0, 0, 0);
      acc[mf] = c;
    }
  }
  __syncthreads();
  // epilogue: Q,K -> LDS [ch][px]; V -> VBT pixel-major
  unsigned short* QL = (unsigned short*)pool;             // [2][64][80]
  unsigned short* KL = (unsigned short*)(pool + 20480);   // [2][64][80]
  const int px = w * 16 + lo16;
#pragma unroll
  for (int mf = 0; mf < 12; ++mf) {
    const int m0 = mf * 16 + hi4 * 4;
    if (mf < 4) {
#pragma unroll
      for (int r = 0; r < 4; ++r) {
        unsigned short h, m2; split2(acc[mf][r] + bq[m0 + r], h, m2);
        QL[(m0 + r) * 80 + px] = h; QL[5120 + (m0 + r) * 80 + px] = m2;
      }
    } else if (mf < 8) {
#pragma unroll
      for (int r = 0; r < 4; ++r) {
        unsigned short h, m2; split2(acc[mf][r] + bk[m0 - 64 + r], h, m2);
        KL[(m0 - 64 + r) * 80 + px] = h; KL[5120 + (m0 - 64 + r) * 80 + px] = m2;
      }
    } else {
      us4 hv, mv;
#pragma unroll
      for (int r = 0; r < 4; ++r) {
        unsigned short h, m2; split2(acc[mf][r] + bv[m0 - 128 + r], h, m2);
        hv[r] = h; mv[r] = m2;
      }
      const size_t vo = ((size_t)b * 4096 + nt * 64 + px) * 64 + (m0 - 128);
      *(us4*)(VBT + vo) = hv;
      *(us4*)(VBT + 1048576 + vo) = mv;
    }
  }
  __syncthreads();
  // coalesced transpose-write to channel-major Q/K
  { const int ch = t >> 2, px0 = (t & 3) * 16;
#pragma unroll
    for (int lev = 0; lev < 2; ++lev) {
      const us8 q0 = *(const us8*)&QL[lev * 5120 + ch * 80 + px0];
      const us8 q1 = *(const us8*)&QL[lev * 5120 + ch * 80 + px0 + 8];
      unsigned short* qd = QCM + (size_t)lev * 1048576 + ((size_t)b * 64 + ch) * 4096 + nt * 64 + px0;
      *(us8*)qd = q0; *(us8*)(qd + 8) = q1;
      const us8 k0v = *(const us8*)&KL[lev * 5120 + ch * 80 + px0];
      const us8 k1v = *(const us8*)&KL[lev * 5120 + ch * 80 + px0 + 8];
      unsigned short* kd = KBC + (size_t)lev * 1048576 + ((size_t)b * 64 + ch) * 4096 + nt * 64 + px0;
      *(us8*)kd = k0v; *(us8*)(kd + 8) = k1v;
    } }
}

// ---------------- kB: S[i][j] += sum_c Q[i][64a+c] * Kconv[a][64c+j]  (block = (b, channel a)) ----------------
__global__ __launch_bounds__(256) void k_sS(char* __restrict__ ws, int layer) {
  __shared__ __align__(16) unsigned short KL2[2 * 4096];
  unsigned short* QCM = (unsigned short*)(ws + OFF_QCM);
  unsigned short* KBC = (unsigned short*)(ws + OFF_KBC);
  float* Sb = (float*)(ws + OFF_SBUF);
  const int t = threadIdx.x;
  const int b = blockIdx.x >> 6, a = blockIdx.x & 63;
  const int w = t >> 6, lane = t & 63, lo16 = lane & 15, hi4 = lane >> 4;
  { const int off = t * 16;
#pragma unroll
    for (int lev = 0; lev < 2; ++lev) {
      const us8 v0 = *(const us8*)(KBC + (size_t)lev * 1048576 + ((size_t)b * 64 + a) * 4096 + off);
      const us8 v1 = *(const us8*)(KBC + (size_t)lev * 1048576 + ((size_t)b * 64 + a) * 4096 + off + 8);
      *(us8*)&KL2[lev * 4096 + off] = v0;
      *(us8*)&KL2[lev * 4096 + off + 8] = v1;
    } }
  __syncthreads();
  f32x4 sacc[4];
#pragma unroll
  for (int jf = 0; jf < 4; ++jf) sacc[jf] = (f32x4)0.f;
#pragma unroll
  for (int kc = 0; kc < 2; ++kc) {
    const size_t qoff = ((size_t)b * 64 + w * 16 + lo16) * 4096 + a * 64 + kc * 32 + hi4 * 8;
    const short8 qh = *(const short8*)(QCM + qoff);
    const short8 qm = *(const short8*)(QCM + 1048576 + qoff);
#pragma unroll
    for (int jf = 0; jf < 4; ++jf) {
      short8 kh, km;
#pragma unroll
      for (int u = 0; u < 8; ++u) {
        const int idx = (kc * 32 + hi4 * 8 + u) * 64 + jf * 16 + lo16;
        kh[u] = (short)KL2[idx];
        km[u] = (short)KL2[4096 + idx];
      }
      f32x4 c = sacc[jf];
      c = MFMA(qh, kh, c, 0, 0, 0);
      c = MFMA(qh, km, c, 0, 0, 0);
      c = MFMA(qm, kh, c, 0, 0, 0);
      c = MFMA(qm, km, c, 0, 0, 0);
      sacc[jf] = c;
    }
  }
  float* Sl = Sb + ((size_t)layer * 4 + b) * 4096;
#pragma unroll
  for (int jf = 0; jf < 4; ++jf)
#pragma unroll
    for (int r = 0; r < 4; ++r)
      unsafeAtomicAdd(&Sl[(w * 16 + hi4 * 4 + r) * 64 + jf * 16 + lo16], sacc[jf][r]);
}

// ---------------- kC: softmax + A=wts@V + P'=Wr@A+br+P + fused next-slot stats ----------------
__global__ __launch_bounds__(256) void k_awrC(const float* __restrict__ x,
                                              const float* __restrict__ br,
                                              const float* __restrict__ Wf,
                                              const float* __restrict__ bf,
                                              char* __restrict__ ws, int layer) {
  __shared__ __align__(16) float WfT[4096];
  __shared__ __align__(16) char scr[40960];
  unsigned short* WRH = (unsigned short*)(ws + OFF_WRH);
  unsigned short* VBT = (unsigned short*)(ws + OFF_VBT);
  float* Sb = (float*)(ws + OFF_SBUF);
  double* patchS = (double*)(ws + OFF_PATCH);
  float* PB = (float*)(ws + OFF_PB);
  const int t = threadIdx.x;
  const int b = blockIdx.x >> 6, y = blockIdx.x & 63;
  const int w = t >> 6, lane = t & 63, lo16 = lane & 15, hi4 = lane >> 4;

  // build WfT [256c][16o] (needed only when layer<3 for stats, but cheap)
  {
    float* WfT2 = (float*)scr;
    for (int r = 0; r < 16; ++r) {
      int idx = r * 256 + t;
      WfT2[(idx >> 8) * 257 + (idx & 255)] = Wf[idx];
    }
    __syncthreads();
    for (int r = 0; r < 16; ++r) {
      int idx = r * 256 + t;
      int c = idx >> 4, o = idx & 15;
      WfT[c * 16 + o] = WfT2[o * 257 + c];
    }
    __syncthreads();
  }

  float* Sf = (float*)scr;                                // [64][68]
  unsigned short* wtsL = (unsigned short*)(scr + 20480);  // [2][64][80]
  const float* Sl = Sb + ((size_t)layer * 4 + b) * 4096;
  { const int i2 = t >> 2, jg = (t & 3) * 16;
#pragma unroll
    for (int u = 0; u < 4; ++u) {
      const float4 v = *(const float4*)(Sl + i2 * 64 + jg + u * 4);
      Sf[(jg + u * 4 + 0) * 68 + i2] = v.x;
      Sf[(jg + u * 4 + 1) * 68 + i2] = v.y;
      Sf[(jg + u * 4 + 2) * 68 + i2] = v.z;
      Sf[(jg + u * 4 + 3) * 68 + i2] = v.w;
    } }
  __syncthreads();
  if (t < 64) {
    float* rowp = &Sf[t * 68];
    float mx = -1e30f;
#pragma unroll
    for (int i = 0; i < 64; ++i) mx = fmaxf(mx, rowp[i]);
    float sum = 0.f;
#pragma unroll
    for (int i = 0; i < 64; ++i) {
      const float e = __expf(rowp[i] - mx);
      rowp[i] = e; sum += e;
    }
    const float inv = 1.f / sum;
#pragma unroll
    for (int i = 0; i < 64; ++i) rowp[i] *= inv;
  }
  __syncthreads();
  { const int i2 = t >> 2, jg = (t & 3) * 16;
#pragma unroll
    for (int u = 0; u < 2; ++u) {
      us8 hv, mv;
#pragma unroll
      for (int jj = 0; jj < 8; ++jj) {
        unsigned short h, m; split2(Sf[(jg + u * 8 + jj) * 68 + i2], h, m);
        hv[jj] = h; mv[jj] = m;
      }
      *(us8*)&wtsL[i2 * 80 + jg + u * 8] = hv;
      *(us8*)&wtsL[5120 + i2 * 80 + jg + u * 8] = mv;
    } }
  __syncthreads();
  const int pxw = w * 16 + lo16;
  f32x4 aacc[4];
#pragma unroll
  for (int if4 = 0; if4 < 4; ++if4) aacc[if4] = (f32x4)0.f;
  const size_t vrow = ((size_t)b * 4096 + y * 64 + pxw) * 64;
#pragma unroll
  for (int kc = 0; kc < 2; ++kc) {
    const short8 vh = *(const short8*)(VBT + vrow + kc * 32 + hi4 * 8);
    const short8 vm = *(const short8*)(VBT + 1048576 + vrow + kc * 32 + hi4 * 8);
#pragma unroll
    for (int if4 = 0; if4 < 4; ++if4) {
      const short8 wh = *(const short8*)&wtsL[(if4 * 16 + lo16) * 80 + kc * 32 + hi4 * 8];
      const short8 wm = *(const short8*)&wtsL[5120 + (if4 * 16 + lo16) * 80 + kc * 32 + hi4 * 8];
      f32x4 c = aacc[if4];
      c = MFMA(wh, vh, c, 0, 0, 0);
      c = MFMA(wh, vm, c, 0, 0, 0);
      c = MFMA(wm, vh, c, 0, 0, 0);
      c = MFMA(wm, vm, c, 0, 0, 0);
      aacc[if4] = c;
    }
  }
  __syncthreads();
  unsigned short* AL = (unsigned short*)scr;   // [2][64px][80i]
#pragma unroll
  for (int if4 = 0; if4 < 4; ++if4)
#pragma unroll
    for (int r = 0; r < 4; ++r) {
      unsigned short h, m; split2(aacc[if4][r], h, m);
      AL[pxw * 80 + if4 * 16 + hi4 * 4 + r] = h;
      AL[5120 + pxw * 80 + if4 * 16 + hi4 * 4 + r] = m;
    }
  __syncthreads();
  f32x4 oacc[16];
#pragma unroll
  for (int of = 0; of < 16; ++of) oacc[of] = (f32x4)0.f;
#pragma unroll
  for (int kc = 0; kc < 2; ++kc) {
    const short8 ah = *(const short8*)&AL[pxw * 80 + kc * 32 + hi4 * 8];
    const short8 am = *(const short8*)&AL[5120 + pxw * 80 + kc * 32 + hi4 * 8];
#pragma unroll
    for (int of = 0; of < 16; ++of) {
      const int o = of * 16 + lo16;
      const short8 rh = *(const short8*)(WRH + o * 64 + kc * 32 + hi4 * 8);
      const short8 rm = *(const short8*)(WRH + 16384 + o * 64 + kc * 32 + hi4 * 8);
      const short8 rl = *(const short8*)(WRH + 32768 + o * 64 + kc * 32 + hi4 * 8);
      f32x4 c = oacc[of];
      c = MFMA(rh, ah, c, 0, 0, 0);
      c = MFMA(rh, am, c, 0, 0, 0);
      c = MFMA(rm, ah, c, 0, 0, 0);
      c = MFMA(rm, am, c, 0, 0, 0);
      c = MFMA(rl, ah, c, 0, 0, 0);
      oacc[of] = c;
    }
  }
  float* PL = (float*)(scr + 20480);           // [64px][68]
  float* PBl = PB + (size_t)layer * 4194304;
  const float* prevP = PB + (size_t)(layer - 1) * 4194304;
  float po[16];
#pragma unroll
  for (int o = 0; o < 16; ++o) po[o] = 0.f;
  const int px = t & 63, cgq = t >> 6;
  const int c16 = cgq * 16;
  for (int oc = 0; oc < 4; ++oc) {
    __syncthreads();
#pragma unroll
    for (int q = 0; q < 4; ++q) {
      const int of = oc * 4 + q;
#pragma unroll
      for (int r = 0; r < 4; ++r)
        PL[pxw * 68 + q * 16 + hi4 * 4 + r] = oacc[of][r] + br[oc * 64 + q * 16 + hi4 * 4 + r];
    }
    __syncthreads();
    float vals[16];
    if (layer == 0) {
      const size_t xb0 = ((size_t)b * 256 + oc * 64 + c16) * 65536
                       + (size_t)(192 + y) * 256 + 192 + px;
#pragma unroll
      for (int cc = 0; cc < 16; ++cc)
        vals[cc] = PL[px * 68 + c16 + cc] + x[xb0 + (size_t)cc * 65536];
    } else {
      const float* pp = prevP + ((size_t)b * 4096 + y * 64 + px) * 256 + oc * 64 + c16;
#pragma unroll
      for (int u = 0; u < 4; ++u) {
        const float4 pv = *(const float4*)(pp + u * 4);
        vals[u * 4 + 0] = PL[px * 68 + c16 + u * 4 + 0] + pv.x;
        vals[u * 4 + 1] = PL[px * 68 + c16 + u * 4 + 1] + pv.y;
        vals[u * 4 + 2] = PL[px * 68 + c16 + u * 4 + 2] + pv.z;
        vals[u * 4 + 3] = PL[px * 68 + c16 + u * 4 + 3] + pv.w;
      }
    }
    float* dstP = PBl + ((size_t)b * 4096 + y * 64 + px) * 256 + oc * 64 + c16;
#pragma unroll
    for (int u = 0; u < 4; ++u) {
      float4 fv;
      fv.x = vals[u * 4 + 0]; fv.y = vals[u * 4 + 1];
      fv.z = vals[u * 4 + 2]; fv.w = vals[u * 4 + 3];
      *(float4*)(dstP + u * 4) = fv;
    }
    if (layer < 3) {
#pragma unroll
      for (int cc = 0; cc < 16; ++cc) {
        const float* wc = &WfT[(oc * 64 + c16 + cc) * 16];
#pragma unroll
        for (int o = 0; o < 16; ++o) po[o] += wc[o] * vals[cc];
      }
    }
  }
  if (layer < 3) {
    __syncthreads();
    float* part = (float*)scr;
#pragma unroll
    for (int o = 0; o < 16; ++o) part[(cgq * 64 + px) * 17 + o] = po[o];
    __syncthreads();
    // reduce: slot layer+1
    const int oo = t & 15, pxg = t >> 4;
    double s1 = 0.0, s2 = 0.0;
    const float bo = bf[oo];
#pragma unroll
    for (int j = 0; j < 4; ++j) {
      const int p = pxg * 4 + j;
      const float yv = part[p * 17 + oo] + part[(64 + p) * 17 + oo]
                     + part[(128 + p) * 17 + oo] + part[(192 + p) * 17 + oo] + bo;
      const double vd = (double)yv;
      s1 += vd; s2 += vd * vd;
    }
    double* red = (double*)(scr + 17408);
    red[(oo * 16 + pxg) * 2] = s1;
    red[(oo * 16 + pxg) * 2 + 1] = s2;
    __syncthreads();
    if (t < 32) {
      const int o = t >> 1, wh = t & 1;
      double s = 0.0;
#pragma unroll
      for (int g = 0; g < 16; ++g) s += red[(o * 16 + g) * 2 + wh];
      unsafeAtomicAdd(&patchS[(size_t)(layer + 1) * 128 + (b * 16 + o) * 2 + wh], s);
    }
  }
}

// ---------------- selection: decision + write chosen P_j into out patch ----------------
__global__ __launch_bounds__(256) void k_sel(float* __restrict__ out, char* __restrict__ ws) {
  __shared__ __align__(16) float T[64 * 68];
  const double* fullS  = (const double*)(ws + OFF_FULL);
  const double* patchS = (const double*)(ws + OFF_PATCH);
  const float* PB = (const float*)(ws + OFF_PB);
  const int t = threadIdx.x;
  const int b2 = blockIdx.x >> 6, y = blockIdx.x & 63;
  const int lane = t & 63;

  int jsel = 4;
  {
    const int k = lane;
    const double fs = fullS[2 * k], fq = fullS[2 * k + 1];
    const double m2 = fs * (1.0 / 65536.0);
    const double v2 = fq * (1.0 / 65536.0) - m2 * m2;
#pragma unroll
    for (int l = 0; l < 4; ++l) {
      const double* ps = patchS + (size_t)l * 128;
      const double s1 = ps[2 * k], s2 = ps[2 * k + 1];
      const double m1 = s1 * (1.0 / 4096.0);
      const double v1 = s2 * (1.0 / 4096.0) - m1 * m1;
      const double gm = (4096.0 * m1 + 65536.0 * m2) * (1.0 / 69632.0);
      const double d1 = m1 - gm, d2 = m2 - gm;
      const double ssb = 4096.0 * d1 * d1 + 65536.0 * d2 * d2;
      const double ssw = 4096.0 * v1 + 65536.0 * v2;
      const double F = ssb * (69630.0 / ssw);
      const unsigned long long bal = __ballot(F > FCRIT);
      if (2 * __popcll(bal) >= 64 && jsel == 4) jsel = l;
    }
  }
  if (jsel == 0) return;   // out already holds x in the patch region (k_main wrote it)
  const float* src = PB + (size_t)(jsel - 1) * 4194304;
  for (int oc = 0; oc < 4; ++oc) {
    __syncthreads();
    { const int pxl = t >> 2, og = (t & 3) * 16;
#pragma unroll
      for (int u = 0; u < 4; ++u) {
        const float4 v = *(const float4*)(src + ((size_t)b2 * 4096 + y * 64 + pxl) * 256
                                          + oc * 64 + og + u * 4);
        *(float4*)&T[pxl * 68 + og + u * 4] = v;
      } }
    __syncthreads();
    { const int ol = t & 63, pg = t >> 6;
      float* op = out + (((size_t)b2 * 256 + oc * 64 + ol) * 256 + 192 + y) * 256 + 192 + pg * 16;
#pragma unroll
      for (int u4 = 0; u4 < 4; ++u4) {
        float4 v;
        v.x = T[(pg * 16 + u4 * 4 + 0) * 68 + ol];
        v.y = T[(pg * 16 + u4 * 4 + 1) * 68 + ol];
        v.z = T[(pg * 16 + u4 * 4 + 2) * 68 + ol];
        v.w = T[(pg * 16 + u4 * 4 + 3) * 68 + ol];
        *(float4*)(op + u4 * 4) = v;
      } }
  }
}

// ---------------- launch ----------------
extern "C" void kernel_launch(void* const* d_in, const int* in_sizes, int n_in,
                              void* d_out, int out_size, void* d_ws, size_t ws_size,
                              hipStream_t stream) {
  const float* x  = (const float*)d_in[0];
  const float* Wq = (const float*)d_in[1];
  const float* bq = (const float*)d_in[2];
  const float* Wk = (const float*)d_in[3];
  const float* bk = (const float*)d_in[4];
  const float* Wv = (const float*)d_in[5];
  const float* bv = (const float*)d_in[6];
  const float* Wr = (const float*)d_in[7];
  const float* br = (const float*)d_in[8];
  const float* Wf = (const float*)d_in[9];
  const float* bf = (const float*)d_in[10];
  float* out = (float*)d_out;
  char* ws = (char*)d_ws;

  double* fullS  = (double*)(ws + OFF_FULL);
  double* patchS = (double*)(ws + OFF_PATCH);

  (void)hipMemsetAsync(ws, 0, ZERO_BYTES, stream);
  k_wcvt<<<256, 256, 0, stream>>>(Wq, Wk, Wv, Wr, ws);
  k_main<<<512, 256, 0, stream>>>(x, Wf, bf, out, fullS, patchS);
  for (int l = 0; l < 4; ++l) {
    k_qkvA<<<256, 256, 0, stream>>>(x, bq, bk, bv, ws, l);
    k_sS<<<256, 256, 0, stream>>>(ws, l);
    k_awrC<<<256, 256, 0, stream>>>(x, br, Wf, bf, ws, l);
  }
  k_sel<<<256, 256, 0, stream>>>(out, ws);
}